// Round 14
// baseline (431.421 us; speedup 1.0000x reference)
//
#include <hip/hip_runtime.h>

// PRODUCTION kernel (round-4 mapping) + NT stores only. (Resubmit — rounds
// 5-13 all failed on infrastructure; no data since round 4.)
// Round-3 evidence: NT on loads+stores cost +35 us — attributed to load-side
// NT bypassing L3-resident input (harness restores d_in right before each
// timed launch). This round A/Bs the other half: NORMAL loads (keep L3 hits)
// + NONTEMPORAL stores (output written once, never re-read -> no-allocate
// stores free L3 capacity for the input stream).
//
// x: (16, 256, 128, 128) f32 -> out: (16, 64, 256, 256) f32.
// out[b,c,2i,2j+0]=0.5(a-bb-cc+d)  out[b,c,2i,2j+1]=0.5(a+bb-cc-d)
// out[b,c,2i+1,2j]=0.5(a-bb+cc-d)  out[b,c,2i+1,2j+1]=0.5(a+bb+cc+d)
// a=x[b,c], bb=x[b,c+64], cc=x[b,c+128], d=x[b,c+192].
//
// Mapping: thread = (b,c,i,q), q in [0,64). 4x dense global_load_dwordx2
// (512 B/wave each), 2x dense global_store_dwordx4 (1024 B/wave each = one
// full output row per wave per store).

typedef float f32x2 __attribute__((ext_vector_type(2)));
typedef float f32x4 __attribute__((ext_vector_type(4)));

__global__ __launch_bounds__(256) void IWT_kernel(const float* __restrict__ x,
                                                  float* __restrict__ out) {
    const unsigned tid = blockIdx.x * 256u + threadIdx.x;
    // total threads = B*C*H*(W/2) = 16*64*128*64 = 8388608 -> 32768 blocks
    const int q = tid & 63;           // column pair index, 2q in [0,128)
    const int i = (tid >> 6) & 127;   // input row
    const int c = (tid >> 13) & 63;   // output channel
    const int b = tid >> 19;          // batch

    const long long chanStride = 128LL * 128;  // 16384
    const long long inBase =
        (((long long)b * 256 + c) * 128 + i) * 128 + (q << 1);

    const f32x2 a  = *(const f32x2*)(x + inBase);
    const f32x2 bb = *(const f32x2*)(x + inBase + 64  * chanStride);
    const f32x2 cc = *(const f32x2*)(x + inBase + 128 * chanStride);
    const f32x2 d  = *(const f32x2*)(x + inBase + 192 * chanStride);

    const f32x2 h00 = 0.5f * (a - bb - cc + d);
    const f32x2 h01 = 0.5f * (a + bb - cc - d);
    const f32x2 h10 = 0.5f * (a - bb + cc - d);
    const f32x2 h11 = 0.5f * (a + bb + cc + d);

    // out row 2i: [h00[0],h01[0],h00[1],h01[1]] at cols 4q..4q+3
    const long long outRow0 =
        (((long long)b * 64 + c) * 256 + 2 * i) * 256 + (q << 2);

    const f32x4 r0 = {h00.x, h01.x, h00.y, h01.y};
    const f32x4 r1 = {h10.x, h11.x, h10.y, h11.y};

    __builtin_nontemporal_store(r0, (f32x4*)(out + outRow0));
    __builtin_nontemporal_store(r1, (f32x4*)(out + outRow0 + 256));
}

extern "C" void kernel_launch(void* const* d_in, const int* in_sizes, int n_in,
                              void* d_out, int out_size, void* d_ws, size_t ws_size,
                              hipStream_t stream) {
    const float* x = (const float*)d_in[0];
    float* out = (float*)d_out;
    IWT_kernel<<<32768, 256, 0, stream>>>(x, out);
}